// Round 3
// baseline (170.103 us; speedup 1.0000x reference)
//
#include <hip/hip_runtime.h>
#include <math.h>

#define HH 192
#define WW 192
#define CC 64
#define CHW (HH*WW)
#define SS 16
#define NB 12
#define NBLK 144
#define CCH 8            // channels per LDS chunk (halved vs R2 -> 8 WGs/CU)
#define UROW 22          // union region rows
#define LROW 28          // padded LDS row stride in floats (16B aligned)
#define QN 6             // float4 staged per row (24 floats)
#define NSH 49

__device__ __forceinline__ int iclamp(int v, int lo, int hi){ return v<lo?lo:(v>hi?hi:v); }

// EX: column-shift class (-3 left edge, 0 interior, +3 right edge)
// OX: cbase - cbase4 (LDS column offset of first used region column), compile-time
template<int EX, int OX, int NCH>
__device__ __forceinline__ void run_chunks(
    const float* __restrict__ f1b, const float* __restrict__ f2b,
    float* sm, int tid, int c_local, int y, int h8,
    int ys, int xs, int rbase, int ey, int cc0, float acc[NSH])
{
  const int cbase4 = (EX == -3) ? 0 : ((EX == 0) ? (xs - 4) : (WW - LROW + 4)); // 0 / xs-4 / 168

  for (int ch0 = 0; ch0 < NCH; ch0 += CCH) {
    const int cc = cc0 + ch0;
    // ---- stage fm2 union region [cc..cc+7][rbase..][cbase4..+23], float4 both sides
#pragma unroll
    for (int ii = 0; ii < 5; ii++) {
      int i = tid + 256*ii;
      if (i < CCH*UROW*QN) {
        int ch  = i / (UROW*QN);
        int rem = i - ch*(UROW*QN);
        int r   = rem / QN;
        int q   = rem - r*QN;
        *(float4*)&sm[ch*(UROW*LROW) + r*LROW + 4*q] =
          *(const float4*)(f2b + (size_t)(cc+ch)*CHW + (size_t)(rbase+r)*WW + cbase4 + 4*q);
      }
    }
    __syncthreads();

    // ---- fm1 half-row (channel cc+c_local, row ys+y, cols xs+h8..xs+h8+7)
    const float* ap = f1b + (size_t)(cc + c_local)*CHW + (size_t)(ys + y)*WW + xs + h8;
    float a[8];
    {
      float4 v;
      v = *(const float4*)(ap + 0); a[0]=v.x; a[1]=v.y; a[2]=v.z; a[3]=v.w;
      v = *(const float4*)(ap + 4); a[4]=v.x; a[5]=v.y; a[6]=v.z; a[7]=v.w;
    }

    const float* smc = sm + c_local*(UROW*LROW);
#pragma unroll
    for (int t = 0; t < 7; t++) {
      int oyt = iclamp(t + ey, 0, 6);            // runtime row offset (address only)
      const float* wp = smc + (oyt + y)*LROW + h8;
      float w[16];
#pragma unroll
      for (int j = 0; j < 4; j++) {
        float4 v = *(const float4*)(wp + 4*j);   // aligned ds_read_b128
        w[4*j]=v.x; w[4*j+1]=v.y; w[4*j+2]=v.z; w[4*j+3]=v.w;
      }
#pragma unroll
      for (int u = 0; u < 7; u++) {
        const int o = ((u+EX) < 0 ? 0 : ((u+EX) > 6 ? 6 : (u+EX))) + OX;  // compile-time
        float s0 = 0.f, s1 = 0.f;
#pragma unroll
        for (int x = 0; x < 8; x += 2) {
          float d0 = a[x]   - w[o+x];
          float d1 = a[x+1] - w[o+x+1];
          s0 = fmaf(d0, d0, s0);
          s1 = fmaf(d1, d1, s1);
        }
        acc[t*7+u] += s0 + s1;
      }
    }
    __syncthreads();
  }
}

// NZ = z-slices (channel split across grid). NZ=2: write 49 raw partials; NZ=1: raw min.
template<int NZ>
__global__ __launch_bounds__(256) void dist_kernel(
    const float* __restrict__ fm1, const float* __restrict__ fm2,
    float* __restrict__ partial)
{
  __shared__ float sm[CCH*UROW*LROW];   // 19,712 B; reduction buffers overlaid after compute

  const int blk = blockIdx.x;          // 0..143
  const int b   = blockIdx.y;          // 0..7
  const int z   = blockIdx.z;          // 0..NZ-1
  const int by  = blk / NB, bx = blk - by*NB;
  const int ys  = by*SS, xs = bx*SS;
  const int rbase = iclamp(ys-3, 0, HH-UROW);
  const int ey = (ys-3) - rbase;       // in {-3,0,3}

  const int tid  = threadIdx.x;
  const int wv   = tid >> 6;
  const int lane = tid & 63;
  const int c_local = tid >> 5;        // 0..7  channel within chunk
  const int rem  = tid & 31;
  const int y    = rem >> 1;           // 0..15 row within block
  const int h8   = (rem & 1) * 8;      // x-half: cols [h8, h8+8)

  const float* f1b = fm1 + (size_t)b*CC*CHW;
  const float* f2b = fm2 + (size_t)b*CC*CHW;

  const int NCH = CC / NZ;             // channels per WG
  const int cc0 = z * NCH;

  float acc[NSH];
#pragma unroll
  for (int k = 0; k < NSH; k++) acc[k] = 0.f;

  if (bx == 0)
    run_chunks<-3,0,CC/NZ>(f1b, f2b, sm, tid, c_local, y, h8, ys, xs, rbase, ey, cc0, acc);
  else if (bx == NB-1)
    run_chunks< 3,2,CC/NZ>(f1b, f2b, sm, tid, c_local, y, h8, ys, xs, rbase, ey, cc0, acc);
  else
    run_chunks< 0,1,CC/NZ>(f1b, f2b, sm, tid, c_local, y, h8, ys, xs, rbase, ey, cc0, acc);

  // ---- reduce acc[k] across 256 threads (overlay reduction buffers on sm)
  float* red   = sm;                   // [4][NSH]
  float* distk = sm + 4*NSH;           // [NSH]
#pragma unroll
  for (int k = 0; k < NSH; k++) {
    float v = acc[k];
#pragma unroll
    for (int off = 32; off; off >>= 1) v += __shfl_xor(v, off);
    if (lane == 0) red[wv*NSH + k] = v;
  }
  __syncthreads();

  if constexpr (NZ == 2) {
    if (tid < NSH) {
      float s = red[0*NSH+tid] + red[1*NSH+tid] + red[2*NSH+tid] + red[3*NSH+tid];
      partial[((size_t)(b*NBLK + blk)*NZ + z)*NSH + tid] = s;   // raw (unscaled)
    }
  } else {
    if (tid < NSH) distk[tid] = red[0*NSH+tid] + red[1*NSH+tid] + red[2*NSH+tid] + red[3*NSH+tid];
    __syncthreads();
    if (tid < 64) {
      float v = (tid < NSH) ? distk[tid] : __builtin_inff();
#pragma unroll
      for (int off = 32; off; off >>= 1) v = fminf(v, __shfl_xor(v, off));
      if (tid == 0) partial[(size_t)b*NBLK + blk] = v;          // raw min
    }
  }
}

template<int NZ>
__global__ void topk_kernel(const float* __restrict__ partial, float* __restrict__ out)
{
  const int b = blockIdx.x;            // 0..7
  const int lane = threadIdx.x;        // 0..63
  const float INF = __builtin_inff();

  float v0 = INF, v1 = INF, v2 = INF;
  if constexpr (NZ == 2) {
#pragma unroll
    for (int i = 0; i < 3; i++) {
      int blk = lane + 64*i;
      if (blk < NBLK) {
        const float* p = partial + (size_t)(b*NBLK + blk)*2*NSH;
        float m = INF;
        for (int k = 0; k < NSH; k++) m = fminf(m, p[k] + p[k+NSH]);
        if (i == 0) v0 = m; else if (i == 1) v1 = m; else v2 = m;
      }
    }
  } else {
    const float* p = partial + (size_t)b*NBLK;
    v0 = p[lane];
    v1 = p[lane + 64];
    v2 = (lane < 16) ? p[lane + 128] : INF;
  }

  float sum = 0.f;
  for (int it = 0; it < 16; ++it) {
    float lm = fminf(v0, fminf(v1, v2));
    float m = lm;
#pragma unroll
    for (int off = 32; off; off >>= 1) m = fminf(m, __shfl_xor(m, off));
    sum += m;
    unsigned long long mask = __ballot(lm == m);
    int leader = __ffsll(mask) - 1;
    if (lane == leader) {
      if (v0 == m)      v0 = INF;
      else if (v1 == m) v1 = INF;
      else              v2 = INF;
    }
  }
  if (lane == 0) out[b] = sum * (1.0f/((float)CC*SS*SS));
}

extern "C" void kernel_launch(void* const* d_in, const int* in_sizes, int n_in,
                              void* d_out, int out_size, void* d_ws, size_t ws_size,
                              hipStream_t stream)
{
  const float* fm1 = (const float*)d_in[0];
  const float* fm2 = (const float*)d_in[1];
  float* out  = (float*)d_out;
  float* scratch = (float*)d_ws;

  const size_t NEED = (size_t)8 * NBLK * 2 * NSH * sizeof(float);  // 451,584 B
  if (ws_size >= NEED) {
    dist_kernel<2><<<dim3(NBLK, 8, 2), 256, 0, stream>>>(fm1, fm2, scratch);
    topk_kernel<2><<<8, 64, 0, stream>>>(scratch, out);
  } else {
    dist_kernel<1><<<dim3(NBLK, 8, 1), 256, 0, stream>>>(fm1, fm2, scratch);
    topk_kernel<1><<<8, 64, 0, stream>>>(scratch, out);
  }
}

// Round 4
// 118.394 us; speedup vs baseline: 1.4368x; 1.4368x over previous
//
#include <hip/hip_runtime.h>
#include <math.h>

#define HH 192
#define WW 192
#define CC 64
#define CHW (HH*WW)
#define SS 16
#define NB 12
#define NBLK 144
#define CCH 8            // channels per LDS chunk
#define UROW 22          // union region rows
#define LROW 28          // padded LDS row stride (dwords); 4-lane/4-bank uniform spread
#define QN 6             // float4 staged per row (24 floats)
#define NSH 49
#define STAGE_N (CCH*UROW*QN)   // 1056 float4 per chunk

__device__ __forceinline__ int iclamp(int v, int lo, int hi){ return v<lo?lo:(v>hi?hi:v); }

// EX: column-shift class (-3 left, 0 interior, +3 right); OX: compile-time col offset
template<int EX, int OX, int NCH>
__device__ __forceinline__ void run_chunks(
    const float* __restrict__ f1b, const float* __restrict__ f2b,
    float* sm, int tid, int t, int y, int h8, bool active,
    int ys, int xs, int rbase, int ey, int cc0, float acc[7])
{
  const int cbase4 = (EX == -3) ? 0 : ((EX == 0) ? (xs - 4) : (WW - LROW + 4));
  const int oyt = iclamp(t + ey, 0, 6);                 // row offset for this thread's dh
  const float* ap0 = f1b + (size_t)(ys + y)*WW + xs + h8;
  const int wrow = (y + oyt)*LROW + h8;                 // fixed per thread

  for (int ch0 = 0; ch0 < NCH; ch0 += CCH) {
    const int cc = cc0 + ch0;
    // ---- stage fm2 union region [cc..cc+7][rbase..+21][cbase4..+23], float4 both sides
    for (int i = tid; i < STAGE_N; i += 256) {
      int ch  = i / (UROW*QN);
      int rem = i - ch*(UROW*QN);
      int r   = rem / QN;
      int q   = rem - r*QN;
      *(float4*)&sm[ch*(UROW*LROW) + r*LROW + 4*q] =
        *(const float4*)(f2b + (size_t)(cc+ch)*CHW + (size_t)(rbase+r)*WW + cbase4 + 4*q);
    }
    __syncthreads();

    if (active) {
#pragma unroll 2
      for (int c = 0; c < CCH; c++) {
        // fm1 half-row from global (L1/L2-resident; 7x reuse across t)
        const float* ap = ap0 + (size_t)(cc + c)*CHW;
        float a[8];
        {
          float4 v0 = *(const float4*)(ap + 0);
          float4 v1 = *(const float4*)(ap + 4);
          a[0]=v0.x; a[1]=v0.y; a[2]=v0.z; a[3]=v0.w;
          a[4]=v1.x; a[5]=v1.y; a[6]=v1.z; a[7]=v1.w;
        }
        // fm2 row for this thread's dh: 16 floats starting at col h8
        const float* wp = sm + c*(UROW*LROW) + wrow;
        float w[16];
#pragma unroll
        for (int j = 0; j < 4; j++) {
          float4 v = *(const float4*)(wp + 4*j);        // aligned ds_read_b128
          w[4*j]=v.x; w[4*j+1]=v.y; w[4*j+2]=v.z; w[4*j+3]=v.w;
        }
#pragma unroll
        for (int u = 0; u < 7; u++) {
          const int o = ((u+EX) < 0 ? 0 : ((u+EX) > 6 ? 6 : (u+EX))) + OX;  // compile-time
          float s0 = 0.f, s1 = 0.f;
#pragma unroll
          for (int x = 0; x < 8; x += 2) {
            float d0 = a[x]   - w[o+x];
            float d1 = a[x+1] - w[o+x+1];
            s0 = fmaf(d0, d0, s0);
            s1 = fmaf(d1, d1, s1);
          }
          acc[u] += s0 + s1;
        }
      }
    }
    __syncthreads();
  }
}

// NZ: channel split across grid.z. NZ=2: write 49 raw partials; NZ=1: raw min only.
template<int NZ>
__global__ __launch_bounds__(256, 8) void dist_kernel(
    const float* __restrict__ fm1, const float* __restrict__ fm2,
    float* __restrict__ partial)
{
  __shared__ float sm[CCH*UROW*LROW];   // 19,712 B; distk overlaid after compute

  const int blk = blockIdx.x;          // 0..143
  const int b   = blockIdx.y;          // 0..7
  const int z   = blockIdx.z;          // 0..NZ-1
  const int by  = blk / NB, bx = blk - by*NB;
  const int ys  = by*SS, xs = bx*SS;
  const int rbase = iclamp(ys-3, 0, HH-UROW);
  const int ey = (ys-3) - rbase;       // in {-3,0,3}

  const int tid = threadIdx.x;
  const int t   = tid >> 5;            // 0..7 ; t<7 active (dh = t-3)
  const int y   = (tid & 31) >> 1;     // 0..15 row within block
  const int h8  = (tid & 1) * 8;       // x-half: cols [h8, h8+8)
  const bool active = (t < 7);

  const float* f1b = fm1 + (size_t)b*CC*CHW;
  const float* f2b = fm2 + (size_t)b*CC*CHW;

  const int cc0 = z * (CC/NZ);

  float acc[7];
#pragma unroll
  for (int k = 0; k < 7; k++) acc[k] = 0.f;

  if (bx == 0)
    run_chunks<-3,0,CC/NZ>(f1b, f2b, sm, tid, t, y, h8, active, ys, xs, rbase, ey, cc0, acc);
  else if (bx == NB-1)
    run_chunks< 3,2,CC/NZ>(f1b, f2b, sm, tid, t, y, h8, active, ys, xs, rbase, ey, cc0, acc);
  else
    run_chunks< 0,1,CC/NZ>(f1b, f2b, sm, tid, t, y, h8, active, ys, xs, rbase, ey, cc0, acc);

  // ---- reduce acc[u] over each 32-lane t-group; leaders write distk[t*7+u]
  float* distk = sm;                   // overlay (past final barrier of run_chunks)
#pragma unroll
  for (int u = 0; u < 7; u++) {
    float v = acc[u];
#pragma unroll
    for (int off = 16; off; off >>= 1) v += __shfl_xor(v, off);
    if (active && (tid & 31) == 0) distk[t*7 + u] = v;
  }
  __syncthreads();

  if constexpr (NZ == 2) {
    if (tid < NSH)
      partial[((size_t)(b*NBLK + blk)*NZ + z)*NSH + tid] = distk[tid];   // raw (unscaled)
  } else {
    if (tid < 64) {
      float v = (tid < NSH) ? distk[tid] : __builtin_inff();
#pragma unroll
      for (int off = 32; off; off >>= 1) v = fminf(v, __shfl_xor(v, off));
      if (tid == 0) partial[(size_t)b*NBLK + blk] = v;                   // raw min
    }
  }
}

template<int NZ>
__global__ void topk_kernel(const float* __restrict__ partial, float* __restrict__ out)
{
  const int b = blockIdx.x;            // 0..7
  const int lane = threadIdx.x;        // 0..63
  const float INF = __builtin_inff();

  float v0 = INF, v1 = INF, v2 = INF;
  if constexpr (NZ == 2) {
#pragma unroll
    for (int i = 0; i < 3; i++) {
      int blk = lane + 64*i;
      if (blk < NBLK) {
        const float* p = partial + (size_t)(b*NBLK + blk)*2*NSH;
        float m = INF;
        for (int k = 0; k < NSH; k++) m = fminf(m, p[k] + p[k+NSH]);
        if (i == 0) v0 = m; else if (i == 1) v1 = m; else v2 = m;
      }
    }
  } else {
    const float* p = partial + (size_t)b*NBLK;
    v0 = p[lane];
    v1 = p[lane + 64];
    v2 = (lane < 16) ? p[lane + 128] : INF;
  }

  float sum = 0.f;
  for (int it = 0; it < 16; ++it) {
    float lm = fminf(v0, fminf(v1, v2));
    float m = lm;
#pragma unroll
    for (int off = 32; off; off >>= 1) m = fminf(m, __shfl_xor(m, off));
    sum += m;
    unsigned long long mask = __ballot(lm == m);
    int leader = __ffsll(mask) - 1;
    if (lane == leader) {
      if (v0 == m)      v0 = INF;
      else if (v1 == m) v1 = INF;
      else              v2 = INF;
    }
  }
  if (lane == 0) out[b] = sum * (1.0f/((float)CC*SS*SS));
}

extern "C" void kernel_launch(void* const* d_in, const int* in_sizes, int n_in,
                              void* d_out, int out_size, void* d_ws, size_t ws_size,
                              hipStream_t stream)
{
  const float* fm1 = (const float*)d_in[0];
  const float* fm2 = (const float*)d_in[1];
  float* out  = (float*)d_out;
  float* scratch = (float*)d_ws;

  const size_t NEED = (size_t)8 * NBLK * 2 * NSH * sizeof(float);  // 451,584 B
  if (ws_size >= NEED) {
    dist_kernel<2><<<dim3(NBLK, 8, 2), 256, 0, stream>>>(fm1, fm2, scratch);
    topk_kernel<2><<<8, 64, 0, stream>>>(scratch, out);
  } else {
    dist_kernel<1><<<dim3(NBLK, 8, 1), 256, 0, stream>>>(fm1, fm2, scratch);
    topk_kernel<1><<<8, 64, 0, stream>>>(scratch, out);
  }
}